// Round 4
// baseline (757.678 us; speedup 1.0000x reference)
//
#include <hip/hip_runtime.h>
#include <hip/hip_bf16.h>
#include <stdint.h>

// CrossAttention on MI355X (gfx950), bf16 MFMA pipeline.
// R4: R3's key-split flash (zero LDS in loop, full-rate K=32 PV via C-frag
//   concat) was latency-bound: loads consumed same-iter -> vmcnt(0) stall,
//   MfmaUtil 14%. Fix: register software-pipeline. K/V frags double-buffered
//   in registers (parity arrays, loop fully unrolled); iter i+1's 12 loads
//   issued before iter i's compute -> consuming iter i waits at vmcnt(12),
//   prefetch stays in flight across the ~600cyc body (> L2 ~300cyc). No
//   barriers in loop. ~190 VGPR -> launch_bounds(256,2).

typedef __bf16 bf16_t;
typedef __bf16 bf16x8 __attribute__((ext_vector_type(8)));
typedef __bf16 bf16x4 __attribute__((ext_vector_type(4)));
typedef short  s16x4  __attribute__((ext_vector_type(4)));
typedef float  f32x4  __attribute__((ext_vector_type(4)));

#define BB 4
#define NN 2048
#define KC 2048
#define DD 1024
#define NH 16
#define HD 64
// 0.125 (=HEAD_DIM^-0.5) * log2(e): softmax done in exp2 domain
#define QSCALE 0.18033688011112042f
#define CLIP2  14.426950408889634f

__device__ __forceinline__ f32x4 mfma_16x16x32(bf16x8 a, bf16x8 b, f32x4 c) {
  return __builtin_amdgcn_mfma_f32_16x16x32_bf16(a, b, c, 0, 0, 0);
}

// async global->LDS, 16B per lane; LDS dest is wave-uniform base + lane*16.
__device__ __forceinline__ void gl_lds16(const bf16_t* g, bf16_t* l) {
  __builtin_amdgcn_global_load_lds(
      (const __attribute__((address_space(1))) void*)g,
      (__attribute__((address_space(3))) void*)l, 16, 0, 0);
}

// ---------------- elementwise f32 -> bf16 ----------------
__global__ __launch_bounds__(256) void cvt_f32_bf16(const float* __restrict__ in,
                                                    bf16_t* __restrict__ out, int n4) {
  int i = blockIdx.x * 256 + threadIdx.x;
  if (i >= n4) return;
  float4 v = ((const float4*)in)[i];
  bf16x4 o = {(bf16_t)v.x, (bf16_t)v.y, (bf16_t)v.z, (bf16_t)v.w};
  ((bf16x4*)out)[i] = o;
}

// ---------------- RMSNorm rows of 1024, f32 in -> bf16 out ----------------
__global__ __launch_bounds__(256) void rmsnorm_rows(const float* __restrict__ in,
                                                    bf16_t* __restrict__ out) {
  int row = blockIdx.x, tid = threadIdx.x;
  float4 v = ((const float4*)(in + (size_t)row * DD))[tid];
  float ss = v.x * v.x + v.y * v.y + v.z * v.z + v.w * v.w;
#pragma unroll
  for (int m = 1; m < 64; m <<= 1) ss += __shfl_xor(ss, m);
  __shared__ float wsum[4];
  if ((tid & 63) == 0) wsum[tid >> 6] = ss;
  __syncthreads();
  float total = wsum[0] + wsum[1] + wsum[2] + wsum[3];
  float scale = rsqrtf(total * (1.0f / (float)DD) + 1e-6f);
  bf16x4 o = {(bf16_t)(v.x * scale), (bf16_t)(v.y * scale),
              (bf16_t)(v.z * scale), (bf16_t)(v.w * scale)};
  ((bf16x4*)(out + (size_t)row * DD))[tid] = o;
}

// ---------------- weight transpose: W (R x C) f32 -> WT (C x R) bf16 ----------------
__global__ __launch_bounds__(256) void transpose_w(const float* __restrict__ W,
                                                   bf16_t* __restrict__ WT, int R, int C) {
  __shared__ float tile[32][33];
  int tx = threadIdx.x & 31, ty = threadIdx.x >> 5;
  int r0 = blockIdx.y * 32, c0 = blockIdx.x * 32;
#pragma unroll
  for (int i = 0; i < 4; i++) tile[ty + 8 * i][tx] = W[(size_t)(r0 + ty + 8 * i) * C + c0 + tx];
  __syncthreads();
#pragma unroll
  for (int i = 0; i < 4; i++)
    WT[(size_t)(c0 + ty + 8 * i) * R + r0 + tx] = (bf16_t)tile[tx][ty + 8 * i];
}

// ---------------- GEMM: C(MxN) = (A(MxK) @ Bt(NxK)^T + bias) * alpha ----------------
template <int OUT_F32>
__global__ __launch_bounds__(256, 2) void gemm_bt(const bf16_t* __restrict__ A,
                                                  const bf16_t* __restrict__ Bt,
                                                  const float* __restrict__ bias,
                                                  void* __restrict__ Cout, int M, int N,
                                                  int Kd, float alpha) {
  __shared__ bf16_t As[128 * 32];
  __shared__ bf16_t Bs[128 * 32];
  int tid = threadIdx.x;
  int w = tid >> 6, lane = tid & 63;
  int quad = lane >> 4, l16 = lane & 15;
  int row0 = blockIdx.y * 128, col0 = blockIdx.x * 128;
  int wm = (w >> 1) * 64, wn = (w & 1) * 64;

  f32x4 acc[4][4];
#pragma unroll
  for (int i = 0; i < 4; i++)
#pragma unroll
    for (int j = 0; j < 4; j++) acc[i][j] = (f32x4){0.f, 0.f, 0.f, 0.f};

  for (int kk = 0; kk < Kd; kk += 32) {
#pragma unroll
    for (int call = 0; call < 2; call++) {
      int c = w * 128 + call * 64 + lane;
      gl_lds16(&A[(size_t)(row0 + (c >> 2)) * Kd + kk + (c & 3) * 8],
               &As[(w * 128 + call * 64) * 8]);
      gl_lds16(&Bt[(size_t)(col0 + (c >> 2)) * Kd + kk + (c & 3) * 8],
               &Bs[(w * 128 + call * 64) * 8]);
    }
    __syncthreads();
    bf16x8 af[4], bfr[4];
#pragma unroll
    for (int mi = 0; mi < 4; mi++)
      af[mi] = *(const bf16x8*)&As[(wm + mi * 16 + l16) * 32 + quad * 8];
#pragma unroll
    for (int ni = 0; ni < 4; ni++)
      bfr[ni] = *(const bf16x8*)&Bs[(wn + ni * 16 + l16) * 32 + quad * 8];
#pragma unroll
    for (int mi = 0; mi < 4; mi++)
#pragma unroll
      for (int ni = 0; ni < 4; ni++) acc[mi][ni] = mfma_16x16x32(af[mi], bfr[ni], acc[mi][ni]);
    __syncthreads();
  }

#pragma unroll
  for (int ni = 0; ni < 4; ni++) {
    int col = col0 + wn + ni * 16 + l16;
    float bv = bias[col];
#pragma unroll
    for (int mi = 0; mi < 4; mi++) {
#pragma unroll
      for (int r = 0; r < 4; r++) {
        int row = row0 + wm + mi * 16 + quad * 4 + r;
        float v = (acc[mi][ni][r] + bv) * alpha;
        if (OUT_F32)
          ((float*)Cout)[(size_t)row * N + col] = v;
        else
          ((bf16_t*)Cout)[(size_t)row * N + col] = (bf16_t)v;
      }
    }
  }
}

// ---------------- V repack: kvbuf[b][kc][1024+h*64+hd] -> vT[(b,h)][hd][kc] ----------------
__global__ __launch_bounds__(256) void transpose_v(const bf16_t* __restrict__ kvbuf,
                                                   bf16_t* __restrict__ vT) {
  __shared__ bf16_t tile[64][72];
  int bh = blockIdx.y;
  int b = bh >> 4, h = bh & 15;
  int kc0 = blockIdx.x * 64;
  int tid = threadIdx.x;
#pragma unroll
  for (int i = 0; i < 2; i++) {
    int ch = tid + i * 256;
    int key = ch >> 3, cc = ch & 7;
    *(bf16x8*)&tile[key][cc * 8] =
        *(const bf16x8*)&kvbuf[((size_t)b * KC + kc0 + key) * (2 * DD) + DD + h * HD + cc * 8];
  }
  __syncthreads();
#pragma unroll
  for (int i = 0; i < 2; i++) {
    int ch = tid + i * 256;
    int hd = ch >> 3, cc = ch & 7;
    bf16x8 v;
#pragma unroll
    for (int e = 0; e < 8; e++) v[e] = tile[cc * 8 + e][hd];
    *(bf16x8*)&vT[((size_t)bh * HD + hd) * KC + kc0 + cc * 8] = v;
  }
}

// ---------------- flash attention, key-split + register software pipeline ----------------
// Block: 64 q-rows, 4 waves; wave w owns keys [kc0+w*32, +32) per iter (kc0 += 128).
// All operands in registers; K/V double-buffered by parity, prefetched one iter
// ahead (loop fully unrolled so parity indices fold). PV at K=32 via C-frag
// concat (k-labeling agreement). Cross-wave O reduction via LDS tree at end.
__global__ __launch_bounds__(256, 2) void flash_attn(const bf16_t* __restrict__ qbuf,
                                                     const bf16_t* __restrict__ kvbuf,
                                                     const bf16_t* __restrict__ vT,
                                                     bf16_t* __restrict__ attn_out) {
  __shared__ float Obuf[2][64][68];  // [buf][hd][q]
  __shared__ float rsh[4][64];
  __shared__ float rsinv[64];
  __shared__ bf16_t outS[64][72];

  int tid = threadIdx.x, w = tid >> 6, lane = tid & 63;
  int quad = lane >> 4, l16 = lane & 15;
  int bid = blockIdx.x;  // 2048 blocks; xcd = bid&7 owns 8 whole (b,h)
  int xcd = bid & 7, slot = bid >> 3;
  int bh = xcd * 8 + (slot >> 5);
  int qt = slot & 31;
  int b = bh >> 4, h = bh & 15;
  int n0 = qt * 64;

  const bf16_t* kbase = kvbuf + (size_t)b * KC * (2 * DD) + (size_t)h * HD;
  const bf16_t* vbase = vT + (size_t)bh * HD * KC;

  // Q-frags: B-operand of S^T. B[k=d=quad*8+j][n=query=qi*16+l16].
  bf16x8 qf[4][2];
#pragma unroll
  for (int qi = 0; qi < 4; qi++)
#pragma unroll
    for (int dc = 0; dc < 2; dc++)
      qf[qi][dc] = *(const bf16x8*)&qbuf[((size_t)b * NN + n0 + qi * 16 + l16) * DD + h * HD +
                                         dc * 32 + quad * 8];

  // lane-dependent 32-bit element offsets (SGPR base + VGPR offset form)
  int koff = (w * 32 + l16) * (2 * DD) + quad * 8;       // + g*16*(2*DD) + dc*32 + it*128*(2*DD)
  int voff = l16 * KC + w * 32 + quad * 4;               // + hb*16*KC + it*128 (+16 for half 1)

  bf16x8 kf[2][2][2];  // [parity][g][dc]
  union vu_t { bf16x8 v8; s16x4 h[2]; };
  vu_t vb[2][4];       // [parity][hb]

#define LOAD_KV(p, it)                                                                   \
  {                                                                                      \
    _Pragma("unroll") for (int g = 0; g < 2; g++) _Pragma("unroll")                      \
        for (int dc = 0; dc < 2; dc++) kf[p][g][dc] =                                    \
            *(const bf16x8*)&kbase[koff + (it)*128 * (2 * DD) + g * 16 * (2 * DD) +      \
                                   dc * 32];                                             \
    _Pragma("unroll") for (int hb = 0; hb < 4; hb++) {                                   \
      vb[p][hb].h[0] = *(const s16x4*)&vbase[voff + hb * 16 * KC + (it)*128];            \
      vb[p][hb].h[1] = *(const s16x4*)&vbase[voff + hb * 16 * KC + (it)*128 + 16];       \
    }                                                                                    \
  }

  f32x4 o[4][4];
#pragma unroll
  for (int qi = 0; qi < 4; qi++)
#pragma unroll
    for (int hb = 0; hb < 4; hb++) o[qi][hb] = (f32x4){0.f, 0.f, 0.f, 0.f};
  float rs[4] = {0.f, 0.f, 0.f, 0.f};

  LOAD_KV(0, 0);
#pragma unroll
  for (int it = 0; it < 16; it++) {
    const int p = it & 1;
    if (it + 1 < 16) LOAD_KV(p ^ 1, it + 1);  // prefetch stays in flight (vmcnt(12))
#pragma unroll
    for (int qi = 0; qi < 4; qi++) {
      union { bf16x8 v8; bf16x4 h[2]; } pf;
#pragma unroll
      for (int g = 0; g < 2; g++) {
        f32x4 s = (f32x4){0.f, 0.f, 0.f, 0.f};
        s = mfma_16x16x32(kf[p][g][0], qf[qi][0], s);
        s = mfma_16x16x32(kf[p][g][1], qf[qi][1], s);
        bf16x4 pb;
#pragma unroll
        for (int r = 0; r < 4; r++) {
          float pv = __builtin_amdgcn_exp2f(__builtin_amdgcn_fmed3f(s[r], -CLIP2, CLIP2));
          rs[qi] += pv;
          pb[r] = (bf16_t)pv;
        }
        pf.h[g] = pb;
      }
#pragma unroll
      for (int hb = 0; hb < 4; hb++) o[qi][hb] = mfma_16x16x32(pf.v8, vb[p][hb].v8, o[qi][hb]);
    }
  }

  // ---- cross-wave reduction (each wave covered a different key subset) ----
#pragma unroll
  for (int qi = 0; qi < 4; qi++) {
    float v = rs[qi];
    v += __shfl_xor(v, 16);
    v += __shfl_xor(v, 32);
    if (quad == 0) rsh[w][qi * 16 + l16] = v;
  }
  if (w >= 2) {
#pragma unroll
    for (int qi = 0; qi < 4; qi++)
#pragma unroll
      for (int hb = 0; hb < 4; hb++)
        *(f32x4*)&Obuf[w - 2][hb * 16 + l16][qi * 16 + quad * 4] = o[qi][hb];
  }
  __syncthreads();
  if (w < 2) {
#pragma unroll
    for (int qi = 0; qi < 4; qi++)
#pragma unroll
      for (int hb = 0; hb < 4; hb++)
        o[qi][hb] += *(const f32x4*)&Obuf[w][hb * 16 + l16][qi * 16 + quad * 4];
  }
  if (w == 2) rsinv[lane] = 1.0f / (rsh[0][lane] + rsh[1][lane] + rsh[2][lane] + rsh[3][lane]);
  __syncthreads();
  if (w == 1) {
#pragma unroll
    for (int qi = 0; qi < 4; qi++)
#pragma unroll
      for (int hb = 0; hb < 4; hb++)
        *(f32x4*)&Obuf[0][hb * 16 + l16][qi * 16 + quad * 4] = o[qi][hb];
  }
  __syncthreads();
  if (w == 0) {
#pragma unroll
    for (int qi = 0; qi < 4; qi++) {
      f32x4 ri = *(const f32x4*)&rsinv[qi * 16 + quad * 4];
#pragma unroll
      for (int hb = 0; hb < 4; hb++) {
        f32x4 ov = o[qi][hb] + *(const f32x4*)&Obuf[0][hb * 16 + l16][qi * 16 + quad * 4];
#pragma unroll
        for (int r = 0; r < 4; r++)
          outS[qi * 16 + quad * 4 + r][hb * 16 + l16] = (bf16_t)(ov[r] * ri[r]);
      }
    }
  }
  __syncthreads();
#pragma unroll
  for (int i = 0; i < 2; i++) {
    int idx = tid + i * 256;
    int row = idx >> 3, c = idx & 7;
    *(bf16x8*)&attn_out[((size_t)b * NN + n0 + row) * DD + h * HD + c * 8] =
        *(const bf16x8*)&outS[row][c * 8];
  }
}

__global__ void write_mean(float* out) { out[0] = 1.0f / 2048.0f; }

// ---------------- launch ----------------
extern "C" void kernel_launch(void* const* d_in, const int* in_sizes, int n_in, void* d_out,
                              int out_size, void* d_ws, size_t ws_size, hipStream_t stream) {
  const float* x      = (const float*)d_in[0];
  const float* ctx    = (const float*)d_in[1];
  const float* q_w    = (const float*)d_in[2];
  const float* q_b    = (const float*)d_in[3];
  const float* kv_w   = (const float*)d_in[4];
  const float* kv_b   = (const float*)d_in[5];
  const float* proj_w = (const float*)d_in[6];
  const float* proj_b = (const float*)d_in[7];
  float* out = (float*)d_out;
  char* ws = (char*)d_ws;

  bf16_t* xb    = (bf16_t*)(ws + 0);          // 16 MB, dead after q GEMM
  bf16_t* ctxn  = (bf16_t*)(ws + 16777216);   // 16 MB, dead after kv GEMM
  bf16_t* qwT   = (bf16_t*)(ws + 33554432);   // 2 MB
  bf16_t* kvwT  = (bf16_t*)(ws + 35651584);   // 4 MB
  bf16_t* pwT   = (bf16_t*)(ws + 39845888);   // 2 MB
  bf16_t* qbuf  = (bf16_t*)(ws + 41943040);   // 16 MB
  bf16_t* kvbuf = (bf16_t*)(ws + 58720256);   // 32 MB
  bf16_t* vT       = ctxn;                    // alias: written after ctxn consumed
  bf16_t* attn_out = xb;                      // alias: written after xb consumed

  cvt_f32_bf16<<<8192, 256, 0, stream>>>(x, xb, (BB * NN * DD) / 4);
  rmsnorm_rows<<<BB * KC, 256, 0, stream>>>(ctx, ctxn);
  transpose_w<<<dim3(32, 32), 256, 0, stream>>>(q_w, qwT, DD, DD);
  transpose_w<<<dim3(64, 32), 256, 0, stream>>>(kv_w, kvwT, DD, 2 * DD);
  transpose_w<<<dim3(32, 32), 256, 0, stream>>>(proj_w, pwT, DD, DD);
  // q = (x @ q_w + q_b) * (SCALE*log2e)  -> softmax uses exp2
  gemm_bt<0><<<dim3(8, 64), 256, 0, stream>>>(xb, qwT, q_b, qbuf, BB * NN, DD, DD, QSCALE);
  gemm_bt<0><<<dim3(16, 64), 256, 0, stream>>>(ctxn, kvwT, kv_b, kvbuf, BB * KC, 2 * DD, DD, 1.0f);
  transpose_v<<<dim3(KC / 64, BB * NH), 256, 0, stream>>>(kvbuf, vT);
  flash_attn<<<2048, 256, 0, stream>>>(qbuf, kvbuf, vT, attn_out);
  gemm_bt<1><<<dim3(8, 64), 256, 0, stream>>>(attn_out, pwT, proj_b, out, BB * NN, DD, DD, 1.0f);
  write_mean<<<1, 1, 0, stream>>>(out + (size_t)out_size - 1);
}

// Round 5
// 330.419 us; speedup vs baseline: 2.2931x; 2.2931x over previous
//
#include <hip/hip_runtime.h>
#include <hip/hip_bf16.h>
#include <stdint.h>

// CrossAttention on MI355X (gfx950), bf16 MFMA pipeline.
// R5: flash = R2's proven LDS staging + R3's full-rate K=32 PV concat +
//   qi=4 (wave owns 64 q-rows; per-q LDS reads halved, PV issue count
//   halved). R4's register double-buffer spilled to scratch (589MB WRITE) —
//   reverted; latency hiding comes from LDS staging + 2 blocks/CU overlap.
//   Query-split: no cross-wave O reduction; rs via per-wave LDS (no barrier).

typedef __bf16 bf16_t;
typedef __bf16 bf16x8 __attribute__((ext_vector_type(8)));
typedef __bf16 bf16x4 __attribute__((ext_vector_type(4)));
typedef short  s16x4  __attribute__((ext_vector_type(4)));
typedef float  f32x4  __attribute__((ext_vector_type(4)));

#define BB 4
#define NN 2048
#define KC 2048
#define DD 1024
#define NH 16
#define HD 64
// 0.125 (=HEAD_DIM^-0.5) * log2(e): softmax done in exp2 domain
#define QSCALE 0.18033688011112042f
#define CLIP2  14.426950408889634f

__device__ __forceinline__ f32x4 mfma_16x16x32(bf16x8 a, bf16x8 b, f32x4 c) {
  return __builtin_amdgcn_mfma_f32_16x16x32_bf16(a, b, c, 0, 0, 0);
}

// async global->LDS, 16B per lane; LDS dest is wave-uniform base + lane*16.
__device__ __forceinline__ void gl_lds16(const bf16_t* g, bf16_t* l) {
  __builtin_amdgcn_global_load_lds(
      (const __attribute__((address_space(1))) void*)g,
      (__attribute__((address_space(3))) void*)l, 16, 0, 0);
}

// ---------------- elementwise f32 -> bf16 ----------------
__global__ __launch_bounds__(256) void cvt_f32_bf16(const float* __restrict__ in,
                                                    bf16_t* __restrict__ out, int n4) {
  int i = blockIdx.x * 256 + threadIdx.x;
  if (i >= n4) return;
  float4 v = ((const float4*)in)[i];
  bf16x4 o = {(bf16_t)v.x, (bf16_t)v.y, (bf16_t)v.z, (bf16_t)v.w};
  ((bf16x4*)out)[i] = o;
}

// ---------------- RMSNorm rows of 1024, f32 in -> bf16 out ----------------
__global__ __launch_bounds__(256) void rmsnorm_rows(const float* __restrict__ in,
                                                    bf16_t* __restrict__ out) {
  int row = blockIdx.x, tid = threadIdx.x;
  float4 v = ((const float4*)(in + (size_t)row * DD))[tid];
  float ss = v.x * v.x + v.y * v.y + v.z * v.z + v.w * v.w;
#pragma unroll
  for (int m = 1; m < 64; m <<= 1) ss += __shfl_xor(ss, m);
  __shared__ float wsum[4];
  if ((tid & 63) == 0) wsum[tid >> 6] = ss;
  __syncthreads();
  float total = wsum[0] + wsum[1] + wsum[2] + wsum[3];
  float scale = rsqrtf(total * (1.0f / (float)DD) + 1e-6f);
  bf16x4 o = {(bf16_t)(v.x * scale), (bf16_t)(v.y * scale),
              (bf16_t)(v.z * scale), (bf16_t)(v.w * scale)};
  ((bf16x4*)(out + (size_t)row * DD))[tid] = o;
}

// ---------------- weight transpose: W (R x C) f32 -> WT (C x R) bf16 ----------------
__global__ __launch_bounds__(256) void transpose_w(const float* __restrict__ W,
                                                   bf16_t* __restrict__ WT, int R, int C) {
  __shared__ float tile[32][33];
  int tx = threadIdx.x & 31, ty = threadIdx.x >> 5;
  int r0 = blockIdx.y * 32, c0 = blockIdx.x * 32;
#pragma unroll
  for (int i = 0; i < 4; i++) tile[ty + 8 * i][tx] = W[(size_t)(r0 + ty + 8 * i) * C + c0 + tx];
  __syncthreads();
#pragma unroll
  for (int i = 0; i < 4; i++)
    WT[(size_t)(c0 + ty + 8 * i) * R + r0 + tx] = (bf16_t)tile[tx][ty + 8 * i];
}

// ---------------- GEMM: C(MxN) = (A(MxK) @ Bt(NxK)^T + bias) * alpha ----------------
template <int OUT_F32>
__global__ __launch_bounds__(256, 2) void gemm_bt(const bf16_t* __restrict__ A,
                                                  const bf16_t* __restrict__ Bt,
                                                  const float* __restrict__ bias,
                                                  void* __restrict__ Cout, int M, int N,
                                                  int Kd, float alpha) {
  __shared__ bf16_t As[128 * 32];
  __shared__ bf16_t Bs[128 * 32];
  int tid = threadIdx.x;
  int w = tid >> 6, lane = tid & 63;
  int quad = lane >> 4, l16 = lane & 15;
  int row0 = blockIdx.y * 128, col0 = blockIdx.x * 128;
  int wm = (w >> 1) * 64, wn = (w & 1) * 64;

  f32x4 acc[4][4];
#pragma unroll
  for (int i = 0; i < 4; i++)
#pragma unroll
    for (int j = 0; j < 4; j++) acc[i][j] = (f32x4){0.f, 0.f, 0.f, 0.f};

  for (int kk = 0; kk < Kd; kk += 32) {
#pragma unroll
    for (int call = 0; call < 2; call++) {
      int c = w * 128 + call * 64 + lane;
      gl_lds16(&A[(size_t)(row0 + (c >> 2)) * Kd + kk + (c & 3) * 8],
               &As[(w * 128 + call * 64) * 8]);
      gl_lds16(&Bt[(size_t)(col0 + (c >> 2)) * Kd + kk + (c & 3) * 8],
               &Bs[(w * 128 + call * 64) * 8]);
    }
    __syncthreads();
    bf16x8 af[4], bfr[4];
#pragma unroll
    for (int mi = 0; mi < 4; mi++)
      af[mi] = *(const bf16x8*)&As[(wm + mi * 16 + l16) * 32 + quad * 8];
#pragma unroll
    for (int ni = 0; ni < 4; ni++)
      bfr[ni] = *(const bf16x8*)&Bs[(wn + ni * 16 + l16) * 32 + quad * 8];
#pragma unroll
    for (int mi = 0; mi < 4; mi++)
#pragma unroll
      for (int ni = 0; ni < 4; ni++) acc[mi][ni] = mfma_16x16x32(af[mi], bfr[ni], acc[mi][ni]);
    __syncthreads();
  }

#pragma unroll
  for (int ni = 0; ni < 4; ni++) {
    int col = col0 + wn + ni * 16 + l16;
    float bv = bias[col];
#pragma unroll
    for (int mi = 0; mi < 4; mi++) {
#pragma unroll
      for (int r = 0; r < 4; r++) {
        int row = row0 + wm + mi * 16 + quad * 4 + r;
        float v = (acc[mi][ni][r] + bv) * alpha;
        if (OUT_F32)
          ((float*)Cout)[(size_t)row * N + col] = v;
        else
          ((bf16_t*)Cout)[(size_t)row * N + col] = (bf16_t)v;
      }
    }
  }
}

// ---------------- V repack: kvbuf[b][kc][1024+h*64+hd] -> vT[(b,h)][hd][kc] ----------------
__global__ __launch_bounds__(256) void transpose_v(const bf16_t* __restrict__ kvbuf,
                                                   bf16_t* __restrict__ vT) {
  __shared__ bf16_t tile[64][72];
  int bh = blockIdx.y;
  int b = bh >> 4, h = bh & 15;
  int kc0 = blockIdx.x * 64;
  int tid = threadIdx.x;
#pragma unroll
  for (int i = 0; i < 2; i++) {
    int ch = tid + i * 256;
    int key = ch >> 3, cc = ch & 7;
    *(bf16x8*)&tile[key][cc * 8] =
        *(const bf16x8*)&kvbuf[((size_t)b * KC + kc0 + key) * (2 * DD) + DD + h * HD + cc * 8];
  }
  __syncthreads();
#pragma unroll
  for (int i = 0; i < 2; i++) {
    int ch = tid + i * 256;
    int hd = ch >> 3, cc = ch & 7;
    bf16x8 v;
#pragma unroll
    for (int e = 0; e < 8; e++) v[e] = tile[cc * 8 + e][hd];
    *(bf16x8*)&vT[((size_t)bh * HD + hd) * KC + kc0 + cc * 8] = v;
  }
}

// ---------------- flash attention: query-split, qi=4, LDS-staged K/V ----------------
// Block: 256 thr / 4 waves; wave w owns q-rows [n0+w*64, +64). Per 64-key tile:
// stage K (64x64) + V^T (64 hd x 64 keys) in LDS, wave reads frags once and
// does 64 K=32 MFMAs (32 S^T + 32 PV via C-frag concat; k-label agreement).
// No cross-wave reduction (query-split). Scalar b16 output stores (once).
__global__ __launch_bounds__(256, 2) void flash_attn(const bf16_t* __restrict__ qbuf,
                                                     const bf16_t* __restrict__ kvbuf,
                                                     const bf16_t* __restrict__ vT,
                                                     bf16_t* __restrict__ attn_out) {
  __shared__ bf16_t Ks[64][72];
  __shared__ bf16_t Vs[64][72];   // [hd][key]
  __shared__ float rsinvS[4][64];

  int tid = threadIdx.x, w = tid >> 6, lane = tid & 63;
  int quad = lane >> 4, l16 = lane & 15;
  // 512 blocks; xcd = bid&7 owns 8 whole (b,h): 4MB K+V = one XCD L2.
  int bid = blockIdx.x;
  int xcd = bid & 7, slot = bid >> 3;     // slot in [0,64)
  int bh = xcd * 8 + (slot >> 3);
  int qt = slot & 7;
  int b = bh >> 4, h = bh & 15;
  int n0 = qt * 256 + w * 64;             // wave-private 64 q-rows

  const bf16_t* kbase = kvbuf + (size_t)b * KC * (2 * DD) + (size_t)h * HD;
  const bf16_t* vbase = vT + (size_t)bh * HD * KC;

  // Q-frags: B-operand of S^T. B[k=d=quad*8+j][n=query=qi*16+l16].
  bf16x8 qf[4][2];
#pragma unroll
  for (int qi = 0; qi < 4; qi++)
#pragma unroll
    for (int dc = 0; dc < 2; dc++)
      qf[qi][dc] = *(const bf16x8*)&qbuf[((size_t)b * NN + n0 + qi * 16 + l16) * DD + h * HD +
                                         dc * 32 + quad * 8];

  f32x4 o[4][4];  // [qi][hb]; C: row=quad*4+r = q-within-16, col=l16 = hd-within-16
#pragma unroll
  for (int qi = 0; qi < 4; qi++)
#pragma unroll
    for (int hb = 0; hb < 4; hb++) o[qi][hb] = (f32x4){0.f, 0.f, 0.f, 0.f};
  float rs[4] = {0.f, 0.f, 0.f, 0.f};

  for (int kc0 = 0; kc0 < KC; kc0 += 64) {
    __syncthreads();  // prev iter's frag reads done
#pragma unroll
    for (int i = 0; i < 2; i++) {
      int idx = tid + i * 256;
      int r = idx >> 3, c = idx & 7;
      *(bf16x8*)&Ks[r][c * 8] = *(const bf16x8*)&kbase[(size_t)(kc0 + r) * (2 * DD) + c * 8];
      *(bf16x8*)&Vs[r][c * 8] = *(const bf16x8*)&vbase[(size_t)r * KC + kc0 + c * 8];
    }
    __syncthreads();

    // K frags: A[m=key=l16][k=d=quad*8+j] per 16-key subtile, per d-half.
    bf16x8 kf[4][2];
#pragma unroll
    for (int ki = 0; ki < 4; ki++)
#pragma unroll
      for (int dc = 0; dc < 2; dc++)
        kf[ki][dc] = *(const bf16x8*)&Ks[ki * 16 + l16][dc * 32 + quad * 8];
    // V frags for concat-PV: slot j<4 -> key g*32+quad*4+j; j>=4 -> +16.
    union vu_t { bf16x8 v8; s16x4 h[2]; };
    vu_t vb[2][4];
#pragma unroll
    for (int g = 0; g < 2; g++)
#pragma unroll
      for (int hb = 0; hb < 4; hb++) {
        vb[g][hb].h[0] = *(const s16x4*)&Vs[hb * 16 + l16][g * 32 + quad * 4];
        vb[g][hb].h[1] = *(const s16x4*)&Vs[hb * 16 + l16][g * 32 + quad * 4 + 16];
      }

#pragma unroll
    for (int qi = 0; qi < 4; qi++) {
#pragma unroll
      for (int g = 0; g < 2; g++) {
        union { bf16x8 v8; bf16x4 h[2]; } pf;
#pragma unroll
        for (int sub = 0; sub < 2; sub++) {
          f32x4 s = (f32x4){0.f, 0.f, 0.f, 0.f};
          s = mfma_16x16x32(kf[g * 2 + sub][0], qf[qi][0], s);
          s = mfma_16x16x32(kf[g * 2 + sub][1], qf[qi][1], s);
          bf16x4 pb;
#pragma unroll
          for (int r = 0; r < 4; r++) {
            float pv = __builtin_amdgcn_exp2f(__builtin_amdgcn_fmed3f(s[r], -CLIP2, CLIP2));
            rs[qi] += pv;
            pb[r] = (bf16_t)pv;
          }
          pf.h[sub] = pb;
        }
#pragma unroll
        for (int hb = 0; hb < 4; hb++)
          o[qi][hb] = mfma_16x16x32(pf.v8, vb[g][hb].v8, o[qi][hb]);
      }
    }
  }

  // full row-sums (sum quads; intra-wave LDS broadcast, no barrier needed)
#pragma unroll
  for (int qi = 0; qi < 4; qi++) {
    float v = rs[qi];
    v += __shfl_xor(v, 16);
    v += __shfl_xor(v, 32);
    if (quad == 0) rsinvS[w][qi * 16 + l16] = 1.0f / v;
  }
#pragma unroll
  for (int qi = 0; qi < 4; qi++) {
    f32x4 ri = *(const f32x4*)&rsinvS[w][qi * 16 + quad * 4];
#pragma unroll
    for (int hb = 0; hb < 4; hb++) {
#pragma unroll
      for (int r = 0; r < 4; r++) {
        int row = n0 + qi * 16 + quad * 4 + r;
        int col = h * HD + hb * 16 + l16;
        attn_out[((size_t)b * NN + row) * DD + col] = (bf16_t)(o[qi][hb][r] * ri[r]);
      }
    }
  }
}

__global__ void write_mean(float* out) { out[0] = 1.0f / 2048.0f; }

// ---------------- launch ----------------
extern "C" void kernel_launch(void* const* d_in, const int* in_sizes, int n_in, void* d_out,
                              int out_size, void* d_ws, size_t ws_size, hipStream_t stream) {
  const float* x      = (const float*)d_in[0];
  const float* ctx    = (const float*)d_in[1];
  const float* q_w    = (const float*)d_in[2];
  const float* q_b    = (const float*)d_in[3];
  const float* kv_w   = (const float*)d_in[4];
  const float* kv_b   = (const float*)d_in[5];
  const float* proj_w = (const float*)d_in[6];
  const float* proj_b = (const float*)d_in[7];
  float* out = (float*)d_out;
  char* ws = (char*)d_ws;

  bf16_t* xb    = (bf16_t*)(ws + 0);          // 16 MB, dead after q GEMM
  bf16_t* ctxn  = (bf16_t*)(ws + 16777216);   // 16 MB, dead after kv GEMM
  bf16_t* qwT   = (bf16_t*)(ws + 33554432);   // 2 MB
  bf16_t* kvwT  = (bf16_t*)(ws + 35651584);   // 4 MB
  bf16_t* pwT   = (bf16_t*)(ws + 39845888);   // 2 MB
  bf16_t* qbuf  = (bf16_t*)(ws + 41943040);   // 16 MB
  bf16_t* kvbuf = (bf16_t*)(ws + 58720256);   // 32 MB
  bf16_t* vT       = ctxn;                    // alias: written after ctxn consumed
  bf16_t* attn_out = xb;                      // alias: written after xb consumed

  cvt_f32_bf16<<<8192, 256, 0, stream>>>(x, xb, (BB * NN * DD) / 4);
  rmsnorm_rows<<<BB * KC, 256, 0, stream>>>(ctx, ctxn);
  transpose_w<<<dim3(32, 32), 256, 0, stream>>>(q_w, qwT, DD, DD);
  transpose_w<<<dim3(64, 32), 256, 0, stream>>>(kv_w, kvwT, DD, 2 * DD);
  transpose_w<<<dim3(32, 32), 256, 0, stream>>>(proj_w, pwT, DD, DD);
  // q = (x @ q_w + q_b) * (SCALE*log2e)  -> softmax uses exp2
  gemm_bt<0><<<dim3(8, 64), 256, 0, stream>>>(xb, qwT, q_b, qbuf, BB * NN, DD, DD, QSCALE);
  gemm_bt<0><<<dim3(16, 64), 256, 0, stream>>>(ctxn, kvwT, kv_b, kvbuf, BB * KC, 2 * DD, DD, 1.0f);
  transpose_v<<<dim3(KC / 64, BB * NH), 256, 0, stream>>>(kvbuf, vT);
  flash_attn<<<512, 256, 0, stream>>>(qbuf, kvbuf, vT, attn_out);
  gemm_bt<1><<<dim3(8, 64), 256, 0, stream>>>(attn_out, pwT, proj_b, out, BB * NN, DD, DD, 1.0f);
  write_mean<<<1, 1, 0, stream>>>(out + (size_t)out_size - 1);
}